// Round 3
// baseline (1206.197 us; speedup 1.0000x reference)
//
#include <hip/hip_runtime.h>
#include <stdint.h>
#include <stddef.h>

// Problem constants (from reference): B=2, S=2048, H=2048, NH=16, HD=128, BS=256
constexpr int B_ = 2;
constexpr int S_ = 2048;
constexpr int H_ = 2048;
constexpr int NH_ = 16;
constexpr int HD_ = 128;
constexpr int BS_ = 256;
constexpr float SCALE_ = 0.08838834764831845f;  // 1/sqrt(128)

typedef __bf16 bf16x8 __attribute__((ext_vector_type(8)));
typedef float floatx4 __attribute__((ext_vector_type(4)));
typedef uint16_t u16x8 __attribute__((ext_vector_type(8)));

static __device__ __forceinline__ bf16x8 ld16(const uint16_t* p) {
    return __builtin_bit_cast(bf16x8, *reinterpret_cast<const uint4*>(p));
}
static __device__ __forceinline__ uint16_t f2b(float f) {
    return __builtin_bit_cast(uint16_t, (__bf16)f);  // RNE fptrunc
}

// Load 8 consecutive elements starting at element offset eoff and return them
// as 8 packed bf16 (one uint4). F32=true: fp32 source, convert. false: bf16 src.
template <bool F32>
static __device__ __forceinline__ uint4 ldrow(const void* base, size_t eoff) {
    if constexpr (F32) {
        const float* p = (const float*)base + eoff;
        const float4 lo = *reinterpret_cast<const float4*>(p);
        const float4 hi = *reinterpret_cast<const float4*>(p + 4);
        u16x8 k;
        k[0] = f2b(lo.x); k[1] = f2b(lo.y); k[2] = f2b(lo.z); k[3] = f2b(lo.w);
        k[4] = f2b(hi.x); k[5] = f2b(hi.y); k[6] = f2b(hi.z); k[7] = f2b(hi.w);
        return __builtin_bit_cast(uint4, k);
    } else {
        return *reinterpret_cast<const uint4*>((const uint16_t*)base + eoff);
    }
}

// ---------------------------------------------------------------------------
// GEMM: C[M x N] = A[M x K] * W[N x K]^T   (fp32-or-bf16 in, fp32 acc)
// M = 4096 (B*S), N = K = 2048. Block: 256 thr (4 waves), tile 128x128, BK=64.
// LDS chunks (16B) XOR-swizzled: slot (row, chL) holds global chunk chL^(row&7)
// so both staging writes and frag reads land at <=2-way bank aliasing (free).
// TSTORE=true scatters bf16 C into Vt[B][NH][HD][S] (transposed for PV frags).
// OF32=true writes fp32 C (the final output buffer is float32 per reference).
// ---------------------------------------------------------------------------
template <bool TSTORE, bool AF32, bool WF32, bool OF32>
__global__ __launch_bounds__(256, 2) void gemm_bt(const void* __restrict__ A,
                                                  const void* __restrict__ W,
                                                  void* __restrict__ C) {
    constexpr int K = H_;
    constexpr int N = H_;
    __shared__ uint4 As[1024];  // 128 rows x 8 chunks = 16 KB
    __shared__ uint4 Bs[1024];

    const int tid = threadIdx.x;
    const int lane = tid & 63;
    const int wave = tid >> 6;
    const int col = lane & 15;
    const int quad = lane >> 4;
    const int m0 = blockIdx.y * 128;
    const int n0 = blockIdx.x * 128;
    const int wr = (wave >> 1) * 64;
    const int wc = (wave & 1) * 64;

    floatx4 acc[4][4] = {};

    for (int kb = 0; kb < K; kb += 64) {
        uint4 av[4], bv[4];
#pragma unroll
        for (int i = 0; i < 4; ++i) {
            const int L = tid + i * 256;
            const int row = L >> 3;
            const int gch = (L & 7) ^ (row & 7);
            const size_t off = (size_t)row * K + kb + gch * 8;
            av[i] = ldrow<AF32>(A, (size_t)m0 * K + off);
            bv[i] = ldrow<WF32>(W, (size_t)n0 * K + off);
        }
        __syncthreads();  // previous tile's readers done
#pragma unroll
        for (int i = 0; i < 4; ++i) {
            As[tid + i * 256] = av[i];
            Bs[tid + i * 256] = bv[i];
        }
        __syncthreads();  // tile visible to all waves
#pragma unroll
        for (int ks = 0; ks < 2; ++ks) {
            bf16x8 af[4], bfr[4];
            const int ch = ks * 4 + quad;
#pragma unroll
            for (int mt = 0; mt < 4; ++mt) {
                const int m = wr + mt * 16 + col;
                af[mt] = __builtin_bit_cast(bf16x8, As[m * 8 + (ch ^ (m & 7))]);
            }
#pragma unroll
            for (int nt = 0; nt < 4; ++nt) {
                const int n = wc + nt * 16 + col;
                bfr[nt] = __builtin_bit_cast(bf16x8, Bs[n * 8 + (ch ^ (n & 7))]);
            }
#pragma unroll
            for (int mt = 0; mt < 4; ++mt)
#pragma unroll
                for (int nt = 0; nt < 4; ++nt)
                    acc[mt][nt] = __builtin_amdgcn_mfma_f32_16x16x32_bf16(
                        af[mt], bfr[nt], acc[mt][nt], 0, 0, 0);
        }
    }

#pragma unroll
    for (int mt = 0; mt < 4; ++mt) {
#pragma unroll
        for (int nt = 0; nt < 4; ++nt) {
#pragma unroll
            for (int r = 0; r < 4; ++r) {
                const int row = m0 + wr + mt * 16 + quad * 4 + r;  // C/D: row=quad*4+r
                const int cc = n0 + wc + nt * 16 + col;            //      col=lane&15
                const float v = acc[mt][nt][r];
                if constexpr (OF32) {
                    ((float*)C)[(size_t)row * N + cc] = v;
                } else if constexpr (!TSTORE) {
                    ((uint16_t*)C)[(size_t)row * N + cc] = f2b(v);
                } else {
                    const int b = row >> 11;        // row = b*S + s
                    const int s = row & (S_ - 1);
                    const int h = cc >> 7;          // cc = h*HD + d
                    const int d = cc & (HD_ - 1);
                    ((uint16_t*)C)[((size_t)((b * NH_ + h) * HD_ + d) << 11) + s] = f2b(v);
                }
            }
        }
    }
}

// ---------------------------------------------------------------------------
// Blockwise-softmax attention. Grid: (S/64, NH, B); block 256 thr (4 waves).
// Wave w owns 16 queries. Per kv-block j<=bi: scores via MFMA (K frags straight
// from global), per-256-key softmax in registers (shfl over 16-lane groups),
// P -> LDS (C-layout -> A-layout transform, +16B row pad), PV via MFMA with
// Vt frags from global. Final scale: 1/((bi+1)+1e-6)  [each block softmax sums
// to 1, so the reference's weight-sum normalizer == bi+1].
// ---------------------------------------------------------------------------
__global__ __launch_bounds__(256, 2) void attn_kernel(const uint16_t* __restrict__ Q,
                                                      const uint16_t* __restrict__ Kp,
                                                      const uint16_t* __restrict__ Vt,
                                                      uint16_t* __restrict__ O) {
    // Per-wave P tile: 16 rows x 256 keys bf16, row stride 264 elems (528B pad)
    __shared__ uint4 Pl[4 * 16 * 33];  // 33792 B
    const int lane = threadIdx.x & 63;
    const int wave = threadIdx.x >> 6;
    const int col = lane & 15;
    const int quad = lane >> 4;
    const int b = blockIdx.z;
    const int h = blockIdx.y;
    const int q0 = blockIdx.x * 64 + wave * 16;
    const int bi = blockIdx.x >> 2;  // query 256-block index (uniform per block)

    const uint16_t* Qb = Q + (size_t)b * S_ * H_ + h * HD_;
    const uint16_t* Kb = Kp + (size_t)b * S_ * H_ + h * HD_;
    const uint16_t* Vb = Vt + (size_t)(b * NH_ + h) * HD_ * S_;
    uint16_t* Ob = O + (size_t)b * S_ * H_ + h * HD_;

    // Q a-fragments: m=lane&15 (query), k = ks*32 + quad*8 + j (head dim)
    bf16x8 aq[4];
#pragma unroll
    for (int ks = 0; ks < 4; ++ks)
        aq[ks] = ld16(Qb + (size_t)(q0 + col) * H_ + ks * 32 + quad * 8);

    floatx4 o[8] = {};
    uint16_t* Pw = reinterpret_cast<uint16_t*>(Pl) + wave * 16 * 264;

    for (int j = 0; j <= bi; ++j) {
        // ---- scores: 16 queries x 256 keys ----
        floatx4 s[16];
#pragma unroll
        for (int nt = 0; nt < 16; ++nt) {
            floatx4 a = {};
#pragma unroll
            for (int ks = 0; ks < 4; ++ks) {
                const bf16x8 kf =
                    ld16(Kb + (size_t)(j * BS_ + nt * 16 + col) * H_ + ks * 32 + quad * 8);
                a = __builtin_amdgcn_mfma_f32_16x16x32_bf16(aq[ks], kf, a, 0, 0, 0);
            }
            s[nt] = a * SCALE_;
        }
        // ---- causal mask (diagonal block only) ----
        if (j == bi) {
            const int qq = (q0 & (BS_ - 1)) + quad * 4;
#pragma unroll
            for (int nt = 0; nt < 16; ++nt) {
                const int key = nt * 16 + col;
#pragma unroll
                for (int r = 0; r < 4; ++r)
                    if (key > qq + r) s[nt][r] = -1e30f;
            }
        }
        // ---- per-block softmax, row r spans 16 lanes x 16 frags ----
#pragma unroll
        for (int r = 0; r < 4; ++r) {
            float mx = s[0][r];
#pragma unroll
            for (int nt = 1; nt < 16; ++nt) mx = fmaxf(mx, s[nt][r]);
#pragma unroll
            for (int d = 1; d < 16; d <<= 1) mx = fmaxf(mx, __shfl_xor(mx, d));
            float sm = 0.f;
#pragma unroll
            for (int nt = 0; nt < 16; ++nt) {
                const float p = __expf(s[nt][r] - mx);
                s[nt][r] = p;
                sm += p;
            }
#pragma unroll
            for (int d = 1; d < 16; d <<= 1) sm += __shfl_xor(sm, d);
            const float inv = 1.0f / sm;
            const int rowoff = (quad * 4 + r) * 264;
#pragma unroll
            for (int nt = 0; nt < 16; ++nt)
                Pw[rowoff + nt * 16 + col] = f2b(s[nt][r] * inv);
        }
        __syncthreads();  // P writes -> A-frag reads (uniform trip count)
        // ---- PV: O[16 x 128] += P[16 x 256] * V[256 x 128] ----
        const uint4* Pr = Pl + wave * (16 * 33) + col * 33;  // m=col row
#pragma unroll
        for (int ks = 0; ks < 8; ++ks) {
            const bf16x8 pa = __builtin_bit_cast(bf16x8, Pr[ks * 4 + quad]);
#pragma unroll
            for (int nd = 0; nd < 8; ++nd) {
                const bf16x8 vf =
                    ld16(Vb + (size_t)(nd * 16 + col) * S_ + j * BS_ + ks * 32 + quad * 8);
                o[nd] = __builtin_amdgcn_mfma_f32_16x16x32_bf16(pa, vf, o[nd], 0, 0, 0);
            }
        }
        __syncthreads();  // PV reads done before next iter overwrites P
    }

    const float rn = 1.0f / ((float)(bi + 1) + 1e-6f);
#pragma unroll
    for (int nd = 0; nd < 8; ++nd)
#pragma unroll
        for (int r = 0; r < 4; ++r)
            Ob[(size_t)(q0 + quad * 4 + r) * H_ + nd * 16 + col] = f2b(o[nd][r] * rn);
}

// ---------------------------------------------------------------------------
// d_in: hidden[B,S,H], Wq, Wk, Wv, Wo — ALL FP32 (per reference dtypes).
// d_out: [B,S,H] FP32 (reference output dtype is float32).
// d_ws: Q (16MB) | K (16MB) | Vt (16MB) | O (16MB) = 64 MB bf16.
// ---------------------------------------------------------------------------
extern "C" void kernel_launch(void* const* d_in, const int* in_sizes, int n_in,
                              void* d_out, int out_size, void* d_ws, size_t ws_size,
                              hipStream_t stream) {
    const void* X = d_in[0];
    const void* Wq = d_in[1];
    const void* Wk = d_in[2];
    const void* Wv = d_in[3];
    const void* Wo = d_in[4];

    const size_t elems = (size_t)B_ * S_ * H_;  // 8M
    uint16_t* Qb = (uint16_t*)d_ws;
    uint16_t* Kb = Qb + elems;
    uint16_t* Vt = Kb + elems;
    uint16_t* Ob = Vt + elems;

    dim3 gg(H_ / 128, (B_ * S_) / 128);  // 16 x 32
    gemm_bt<false, true, true, false><<<gg, 256, 0, stream>>>(X, Wq, Qb);
    gemm_bt<false, true, true, false><<<gg, 256, 0, stream>>>(X, Wk, Kb);
    gemm_bt<true, true, true, false><<<gg, 256, 0, stream>>>(X, Wv, Vt);

    dim3 ga(S_ / 64, NH_, B_);  // 32 x 16 x 2
    attn_kernel<<<ga, 256, 0, stream>>>(Qb, Kb, Vt, Ob);

    gemm_bt<false, false, true, true><<<gg, 256, 0, stream>>>(Ob, Wo, d_out);
}

// Round 4
// 691.694 us; speedup vs baseline: 1.7438x; 1.7438x over previous
//
#include <hip/hip_runtime.h>
#include <stdint.h>
#include <stddef.h>

// Problem constants: B=2, S=2048, H=2048, NH=16, HD=128, BS=256
constexpr int B_ = 2;
constexpr int S_ = 2048;
constexpr int H_ = 2048;
constexpr int NH_ = 16;
constexpr int HD_ = 128;
constexpr int BS_ = 256;
constexpr float SCALE_ = 0.08838834764831845f;  // 1/sqrt(128)

typedef __bf16 bf16x8 __attribute__((ext_vector_type(8)));
typedef float floatx4 __attribute__((ext_vector_type(4)));
typedef uint16_t u16x8 __attribute__((ext_vector_type(8)));

static __device__ __forceinline__ bf16x8 ld16(const uint16_t* p) {
    return __builtin_bit_cast(bf16x8, *reinterpret_cast<const uint4*>(p));
}
static __device__ __forceinline__ uint16_t f2b(float f) {
    return __builtin_bit_cast(uint16_t, (__bf16)f);  // RNE fptrunc
}

// 8 elems from fp32 (convert) or bf16 source -> packed bf16 uint4.
template <bool F32>
static __device__ __forceinline__ uint4 ldrow(const void* base, size_t eoff) {
    if constexpr (F32) {
        const float* p = (const float*)base + eoff;
        const float4 lo = *reinterpret_cast<const float4*>(p);
        const float4 hi = *reinterpret_cast<const float4*>(p + 4);
        u16x8 k;
        k[0] = f2b(lo.x); k[1] = f2b(lo.y); k[2] = f2b(lo.z); k[3] = f2b(lo.w);
        k[4] = f2b(hi.x); k[5] = f2b(hi.y); k[6] = f2b(hi.z); k[7] = f2b(hi.w);
        return __builtin_bit_cast(uint4, k);
    } else {
        return *reinterpret_cast<const uint4*>((const uint16_t*)base + eoff);
    }
}

// Async global->LDS, 16B per lane. LDS dest = wave-uniform base + lane*16.
static __device__ __forceinline__ void gld_lds16(const uint16_t* g, const uint4* lds_wave_base) {
    __builtin_amdgcn_global_load_lds(
        (const __attribute__((address_space(1))) uint32_t*)g,
        (__attribute__((address_space(3))) uint32_t*)lds_wave_base,
        16, 0, 0);
}

// fp32 -> bf16 pack, 8 elems/thread. Grid must cover n/8 exactly.
__global__ __launch_bounds__(256) void cvt_kernel(const float* __restrict__ src,
                                                  uint16_t* __restrict__ dst) {
    const size_t i = (size_t)blockIdx.x * 256 + threadIdx.x;
    reinterpret_cast<uint4*>(dst)[i] = ldrow<true>(src, i * 8);
}

// ---------------------------------------------------------------------------
// GEMM: C[M x N] = A[M x K] * W[N x K]^T.  A: bf16 (async global_load_lds,
// XOR-swizzled chunks: LDS slot (row,chL) holds global chunk chL^(row&7) —
// swizzle applied on the GLOBAL side, LDS side is lane-contiguous as required
// by the wave-uniform-base rule).  W: fp32, register-staged + cvt.
// Tile 128x128, BK=64, 4 waves, 4x4 16x16x32 MFMA per wave.
// ---------------------------------------------------------------------------
template <bool TSTORE, bool OF32>
__global__ __launch_bounds__(256, 2) void gemm_bt(const uint16_t* __restrict__ A,
                                                  const void* __restrict__ W,
                                                  void* __restrict__ C) {
    constexpr int K = H_;
    constexpr int N = H_;
    __shared__ uint4 As[1024];  // 128 rows x 8 chunks (16B) = 16 KB
    __shared__ uint4 Bs[1024];

    const int tid = threadIdx.x;
    const int lane = tid & 63;
    const int wave = tid >> 6;
    const int col = lane & 15;
    const int quad = lane >> 4;
    const int m0 = blockIdx.y * 128;
    const int n0 = blockIdx.x * 128;
    const int wr = (wave >> 1) * 64;
    const int wc = (wave & 1) * 64;

    const uint16_t* Abase = A + (size_t)m0 * K;

    floatx4 acc[4][4] = {};

    for (int kb = 0; kb < K; kb += 64) {
        uint4 bv[4];
#pragma unroll
        for (int i = 0; i < 4; ++i) {
            const int L = tid + i * 256;
            const int row = L >> 3;
            const int gch = (L & 7) ^ (row & 7);
            bv[i] = ldrow<true>(W, (size_t)n0 * K + (size_t)row * K + kb + gch * 8);
        }
        __syncthreads();  // prev tile's readers done before LDS overwritten
#pragma unroll
        for (int i = 0; i < 4; ++i) {
            const int L = tid + i * 256;
            const int row = L >> 3;
            const int gch = (L & 7) ^ (row & 7);
            gld_lds16(Abase + (size_t)row * K + kb + gch * 8, &As[i * 256 + wave * 64]);
        }
#pragma unroll
        for (int i = 0; i < 4; ++i) Bs[tid + i * 256] = bv[i];
        __syncthreads();  // drains vmcnt (async LDS loads) + lgkm
#pragma unroll
        for (int ks = 0; ks < 2; ++ks) {
            bf16x8 af[4], bfr[4];
            const int ch = ks * 4 + quad;
#pragma unroll
            for (int mt = 0; mt < 4; ++mt) {
                const int m = wr + mt * 16 + col;
                af[mt] = __builtin_bit_cast(bf16x8, As[m * 8 + (ch ^ (m & 7))]);
            }
#pragma unroll
            for (int nt = 0; nt < 4; ++nt) {
                const int n = wc + nt * 16 + col;
                bfr[nt] = __builtin_bit_cast(bf16x8, Bs[n * 8 + (ch ^ (n & 7))]);
            }
#pragma unroll
            for (int mt = 0; mt < 4; ++mt)
#pragma unroll
                for (int nt = 0; nt < 4; ++nt)
                    acc[mt][nt] = __builtin_amdgcn_mfma_f32_16x16x32_bf16(
                        af[mt], bfr[nt], acc[mt][nt], 0, 0, 0);
        }
    }

#pragma unroll
    for (int mt = 0; mt < 4; ++mt) {
#pragma unroll
        for (int nt = 0; nt < 4; ++nt) {
#pragma unroll
            for (int r = 0; r < 4; ++r) {
                const int row = m0 + wr + mt * 16 + quad * 4 + r;  // C/D: row=quad*4+r
                const int cc = n0 + wc + nt * 16 + col;            //      col=lane&15
                const float v = acc[mt][nt][r];
                if constexpr (OF32) {
                    ((float*)C)[(size_t)row * N + cc] = v;
                } else if constexpr (!TSTORE) {
                    ((uint16_t*)C)[(size_t)row * N + cc] = f2b(v);
                } else {
                    const int b = row >> 11;        // row = b*S + s
                    const int s = row & (S_ - 1);
                    const int h = cc >> 7;          // cc = h*HD + d
                    const int d = cc & (HD_ - 1);
                    ((uint16_t*)C)[((size_t)((b * NH_ + h) * HD_ + d) << 11) + s] = f2b(v);
                }
            }
        }
    }
}

// ---------------------------------------------------------------------------
// Blockwise-softmax attention, pair-balanced, barrier-free.
// Grid: (16 pairs, NH, B); block 256 thr (4 waves), each wave 16 queries.
// Pair p handles q-tile p (bi=p>>2) and q-tile 31-p (bi=7-(p>>2)): exactly 9
// (qtile,j) units per wg -> uniform load. P tile is PER-WAVE private in LDS,
// so no __syncthreads anywhere (in-wave lgkmcnt ordering suffices).
// ---------------------------------------------------------------------------
__global__ __launch_bounds__(256, 2) void attn_kernel(const uint16_t* __restrict__ Q,
                                                      const uint16_t* __restrict__ Kp,
                                                      const uint16_t* __restrict__ Vt,
                                                      uint16_t* __restrict__ O) {
    // Per-wave P tile: 16 rows x 256 keys bf16, row stride 264 elems (528B)
    __shared__ uint4 Pl[4 * 16 * 33];  // 33792 B
    const int lane = threadIdx.x & 63;
    const int wave = threadIdx.x >> 6;
    const int col = lane & 15;
    const int quad = lane >> 4;
    const int b = blockIdx.z;
    const int h = blockIdx.y;
    const int p = blockIdx.x;

    const uint16_t* Qb = Q + (size_t)b * S_ * H_ + h * HD_;
    const uint16_t* Kb = Kp + (size_t)b * S_ * H_ + h * HD_;
    const uint16_t* Vb = Vt + (size_t)(b * NH_ + h) * HD_ * S_;
    uint16_t* Ob = O + (size_t)b * S_ * H_ + h * HD_;

    uint16_t* Pw = reinterpret_cast<uint16_t*>(Pl) + wave * 16 * 264;
    const uint4* Pr = Pl + wave * (16 * 33) + col * 33;  // m=col row

#pragma unroll
    for (int ti = 0; ti < 2; ++ti) {
        const int t = ti ? (31 - p) : p;   // q-tile (64 rows)
        const int bi = t >> 2;             // 256-block index of these queries
        const int q0 = t * 64 + wave * 16;

        // Q a-frags: m=lane&15 (query), k = ks*32 + quad*8 + j
        bf16x8 aq[4];
#pragma unroll
        for (int ks = 0; ks < 4; ++ks)
            aq[ks] = ld16(Qb + (size_t)(q0 + col) * H_ + ks * 32 + quad * 8);

        floatx4 o[8] = {};

        for (int j = 0; j <= bi; ++j) {
            // ---- scores: 16 queries x 256 keys ----
            floatx4 s[16];
#pragma unroll
            for (int nt = 0; nt < 16; ++nt) {
                floatx4 a = {};
#pragma unroll
                for (int ks = 0; ks < 4; ++ks) {
                    const bf16x8 kf =
                        ld16(Kb + (size_t)(j * BS_ + nt * 16 + col) * H_ + ks * 32 + quad * 8);
                    a = __builtin_amdgcn_mfma_f32_16x16x32_bf16(aq[ks], kf, a, 0, 0, 0);
                }
                s[nt] = a * SCALE_;
            }
            // ---- causal mask (diagonal block only) ----
            if (j == bi) {
                const int qq = (q0 & (BS_ - 1)) + quad * 4;
#pragma unroll
                for (int nt = 0; nt < 16; ++nt) {
                    const int key = nt * 16 + col;
#pragma unroll
                    for (int r = 0; r < 4; ++r)
                        if (key > qq + r) s[nt][r] = -1e30f;
                }
            }
            // ---- per-block softmax; row r spans 16 lanes x 16 frags ----
#pragma unroll
            for (int r = 0; r < 4; ++r) {
                float mx = s[0][r];
#pragma unroll
                for (int nt = 1; nt < 16; ++nt) mx = fmaxf(mx, s[nt][r]);
#pragma unroll
                for (int d = 1; d < 16; d <<= 1) mx = fmaxf(mx, __shfl_xor(mx, d));
                float sm = 0.f;
#pragma unroll
                for (int nt = 0; nt < 16; ++nt) {
                    const float pw = __expf(s[nt][r] - mx);
                    s[nt][r] = pw;
                    sm += pw;
                }
#pragma unroll
                for (int d = 1; d < 16; d <<= 1) sm += __shfl_xor(sm, d);
                const float inv = 1.0f / sm;
                const int rowoff = (quad * 4 + r) * 264;
#pragma unroll
                for (int nt = 0; nt < 16; ++nt)
                    Pw[rowoff + nt * 16 + col] = f2b(s[nt][r] * inv);
            }
            // ---- PV: O[16x128] += P[16x256] * V[256x128] (P wave-private) ----
#pragma unroll
            for (int ks = 0; ks < 8; ++ks) {
                const bf16x8 pa = __builtin_bit_cast(bf16x8, Pr[ks * 4 + quad]);
#pragma unroll
                for (int nd = 0; nd < 8; ++nd) {
                    const bf16x8 vf =
                        ld16(Vb + (size_t)(nd * 16 + col) * S_ + j * BS_ + ks * 32 + quad * 8);
                    o[nd] = __builtin_amdgcn_mfma_f32_16x16x32_bf16(pa, vf, o[nd], 0, 0, 0);
                }
            }
        }

        const float rn = 1.0f / ((float)(bi + 1) + 1e-6f);
#pragma unroll
        for (int nd = 0; nd < 8; ++nd)
#pragma unroll
            for (int r = 0; r < 4; ++r)
                Ob[(size_t)(q0 + quad * 4 + r) * H_ + nd * 16 + col] = f2b(o[nd][r] * rn);
    }
}

// ---------------------------------------------------------------------------
// d_in: hidden[B,S,H], Wq, Wk, Wv, Wo — fp32. d_out: [B,S,H] fp32.
// d_ws (64 MB, proven budget): Xb 16MB | Qb 16MB | Kb 16MB | Vt 16MB.
// Ob (attn output, bf16) overlays Xb — Xb is dead after the V GEMM.
// ---------------------------------------------------------------------------
extern "C" void kernel_launch(void* const* d_in, const int* in_sizes, int n_in,
                              void* d_out, int out_size, void* d_ws, size_t ws_size,
                              hipStream_t stream) {
    const float* X = (const float*)d_in[0];
    const void* Wq = d_in[1];
    const void* Wk = d_in[2];
    const void* Wv = d_in[3];
    const void* Wo = d_in[4];

    const size_t elems = (size_t)B_ * S_ * H_;  // 8M
    uint16_t* Xb = (uint16_t*)d_ws;
    uint16_t* Qb = Xb + elems;
    uint16_t* Kb = Qb + elems;
    uint16_t* Vt = Kb + elems;
    uint16_t* Ob = Xb;  // overlay: Xb dead once attn runs

    cvt_kernel<<<(int)(elems / 8 / 256), 256, 0, stream>>>(X, Xb);

    dim3 gg(H_ / 128, (B_ * S_) / 128);  // 16 x 32
    gemm_bt<false, false><<<gg, 256, 0, stream>>>(Xb, Wq, Qb);
    gemm_bt<false, false><<<gg, 256, 0, stream>>>(Xb, Wk, Kb);
    gemm_bt<true, false><<<gg, 256, 0, stream>>>(Xb, Wv, Vt);

    dim3 ga(16, NH_, B_);  // 512 wg, uniform 9 units each
    attn_kernel<<<ga, 256, 0, stream>>>(Qb, Kb, Vt, Ob);

    gemm_bt<false, true><<<gg, 256, 0, stream>>>(Ob, Wo, d_out);
}